// Round 3
// baseline (2049.083 us; speedup 1.0000x reference)
//
#include <hip/hip_runtime.h>

typedef __attribute__((ext_vector_type(4))) float f32x4;
typedef __attribute__((ext_vector_type(8))) short s16x8;
typedef __attribute__((ext_vector_type(4))) short s16x4;

__device__ __forceinline__ short f2bf(float f) {
  union { float f; unsigned u; } v; v.f = f;
  unsigned r = (v.u + 0x7fffu + ((v.u >> 16) & 1u)) >> 16;
  return (short)(r & 0xffffu);
}
__device__ __forceinline__ float bf2f(short s) {
  union { unsigned u; float f; } v; v.u = ((unsigned)(unsigned short)s) << 16;
  return v.f;
}
__device__ __forceinline__ f32x4 mfma16(s16x8 a, s16x8 b, f32x4 c) {
  return __builtin_amdgcn_mfma_f32_16x16x32_bf16(a, b, c, 0, 0, 0);
}

#define AS1(p) ((__attribute__((address_space(1))) void*)(p))
#define AS3(p) ((__attribute__((address_space(3))) void*)(p))

// ---------------- fp32 -> bf16 convert ----------------
__global__ __launch_bounds__(256) void cvt_bf16_kernel(const float* __restrict__ in,
                                                       short* __restrict__ out, long n) {
  long i = ((long)blockIdx.x * 256 + threadIdx.x) * 4;
  if (i + 4 <= n) {
    f32x4 v = *(const f32x4*)(in + i);
    s16x4 o;
    o[0] = f2bf(v[0]); o[1] = f2bf(v[1]); o[2] = f2bf(v[2]); o[3] = f2bf(v[3]);
    *(s16x4*)(out + i) = o;
  }
}

// ---------------- concat 3 bias vectors ----------------
__global__ __launch_bounds__(256) void bias_cat_kernel(const float* __restrict__ bq,
                                                       const float* __restrict__ bk,
                                                       const float* __restrict__ bv,
                                                       float* __restrict__ o) {
  int i = blockIdx.x * 256 + threadIdx.x;
  if (i < 3072) o[i] = (i < 1024) ? bq[i] : ((i < 2048) ? bk[i - 1024] : bv[i - 2048]);
}

// ---------------- rel table prep ----------------
__global__ __launch_bounds__(64) void prep_rel_kernel(
    const float* __restrict__ rq, const float* __restrict__ rk, const float* __restrict__ rv,
    short* __restrict__ relqb, short* __restrict__ relkb, short* __restrict__ relvT,
    float* __restrict__ Dh) {
  int h = blockIdx.x / 240;
  int r = blockIdx.x % 240;
  int d = threadIdx.x;
  float vq = 0.f, vk = 0.f, vv = 0.f;
  if (r < 225) {
    long o = ((long)h * 225 + r) * 64 + d;
    vq = rq[o]; vk = rk[o]; vv = rv[o];
  }
  relqb[((long)h * 240 + r) * 64 + d] = f2bf(vq);
  relkb[((long)h * 240 + r) * 64 + d] = f2bf(vk);
  relvT[((long)h * 64 + d) * 256 + r] = f2bf(vv);
  if (r < 16) relvT[((long)h * 64 + d) * 256 + 240 + r] = 0;
  float p = vq * vk;
  #pragma unroll
  for (int m = 32; m >= 1; m >>= 1) p += __shfl_xor(p, m);
  if (d == 0) Dh[h * 240 + r] = p;
}

// ---------------- GEMM: C = A(M x K, lda) @ Bw(N x K)^T + bias ----------------
// MODE 0: f32 out.  MODE 1: bf16 out.  MODE 2: bf16 out for col<2048, cols>=2048
// go transposed into vT[b][h][d][t] (the QKV projection's v-part).
template<int MODE>
__global__ __launch_bounds__(256) void gemm_bt_kernel(
    const short* __restrict__ A, const short* __restrict__ Bw,
    const float* __restrict__ bias, void* __restrict__ Cout, short* __restrict__ vT,
    int M, int N, int K, int lda) {
  __shared__ __attribute__((aligned(16))) short As[4096];  // 128 x 32
  __shared__ __attribute__((aligned(16))) short Bs[4096];  // 128 x 32
  const int tid = threadIdx.x;
  const int lane = tid & 63;
  const int w = tid >> 6;
  const int wr = w >> 1, wc = w & 1;
  const int l15 = lane & 15, l4 = lane >> 4;
  const int nbn = N >> 7;
  const int nwg = gridDim.x;
  const int bid = blockIdx.x;
  const int swz = ((bid & 7) * (nwg >> 3)) + (bid >> 3);   // XCD swizzle (nwg%8==0)
  const int bm = swz / nbn, bn = swz % nbn;

  const int sr = w * 32 + (lane >> 2);
  const int sc = (lane & 3) * 8;
  const short* ga0 = A  + ((long)(bm * 128 + sr)) * lda + sc;
  const short* gb0 = Bw + ((long)(bn * 128 + sr)) * K + sc;
  const long rowa16 = (long)16 * lda;
  const long rowb16 = (long)16 * K;
  short* la0 = As + w * 1024;
  short* lb0 = Bs + w * 1024;

  f32x4 zero = {0.f, 0.f, 0.f, 0.f};
  f32x4 acc[4][4];
  #pragma unroll
  for (int mi = 0; mi < 4; mi++)
    #pragma unroll
    for (int nj = 0; nj < 4; nj++) acc[mi][nj] = zero;

  for (int k0 = 0; k0 < K; k0 += 32) {
    __builtin_amdgcn_global_load_lds(AS1(ga0 + k0),          AS3(la0),       16, 0, 0);
    __builtin_amdgcn_global_load_lds(AS1(ga0 + rowa16 + k0), AS3(la0 + 512), 16, 0, 0);
    __builtin_amdgcn_global_load_lds(AS1(gb0 + k0),          AS3(lb0),       16, 0, 0);
    __builtin_amdgcn_global_load_lds(AS1(gb0 + rowb16 + k0), AS3(lb0 + 512), 16, 0, 0);
    __syncthreads();
    s16x8 af[4], bfv[4];
    #pragma unroll
    for (int mi = 0; mi < 4; mi++)
      af[mi] = *(const s16x8*)&As[(wr * 64 + mi * 16 + l15) * 32 + l4 * 8];
    #pragma unroll
    for (int nj = 0; nj < 4; nj++)
      bfv[nj] = *(const s16x8*)&Bs[(wc * 64 + nj * 16 + l15) * 32 + l4 * 8];
    #pragma unroll
    for (int mi = 0; mi < 4; mi++)
      #pragma unroll
      for (int nj = 0; nj < 4; nj++)
        acc[mi][nj] = mfma16(af[mi], bfv[nj], acc[mi][nj]);
    __syncthreads();
  }

  const long crow = (long)bm * 128 + wr * 64;
  const int ccol = bn * 128 + wc * 64;
  #pragma unroll
  for (int nj = 0; nj < 4; nj++) {
    const int col = ccol + nj * 16 + l15;
    const float bv = bias[col];
    #pragma unroll
    for (int mi = 0; mi < 4; mi++) {
      #pragma unroll
      for (int j = 0; j < 4; j++) {
        const long row = crow + mi * 16 + l4 * 4 + j;
        float val = acc[mi][nj][j] + bv;
        if (MODE == 2 && ccol >= 2048) {
          const int vc = col - 2048;
          const int h = vc >> 6, d = vc & 63;
          const long b = row >> 6, t = row & 63;
          vT[(((b * 16 + h) * 64) + d) * 64 + t] = f2bf(val);
        } else if (MODE == 0) {
          ((float*)Cout)[row * N + col] = val;
        } else {
          ((short*)Cout)[row * N + col] = f2bf(val);
        }
      }
    }
  }
}

// ---------------- qr/kr producer: out[bl,h,t,r] = A(q or k)[b,t,:]·relT[h,r,:] (+Dadd)
__global__ __launch_bounds__(256) void qrel_kernel(
    const short* __restrict__ qkv, int col_off, const short* __restrict__ relT,
    const float* __restrict__ Dadd, short* __restrict__ outp, int b0) {
  __shared__ __attribute__((aligned(16))) short As[8192];   // 128 x 64, swizzled
  __shared__ __attribute__((aligned(16))) short Bs[15360];  // 240 x 64, swizzled
  const int tid = threadIdx.x, lane = tid & 63, w = tid >> 6;
  const int l15 = lane & 15, l4 = lane >> 4;
  const int bm = blockIdx.x, h = blockIdx.y;

  #pragma unroll
  for (int i = 0; i < 4; i++) {
    int c = tid * 4 + i;                    // 1024 chunks of 16B
    int row = c >> 3, c8 = (c & 7) * 8;
    long g = ((long)(b0 * 64 + bm * 128 + row)) * 3072 + col_off + h * 64 + c8;
    s16x8 v = *(const s16x8*)(qkv + g);
    *(s16x8*)((char*)As + row * 128 + ((c8 * 2) ^ ((row & 7) << 4))) = v;
  }
  #pragma unroll
  for (int i = 0; i < 8; i++) {
    int c = tid + 256 * i;                  // 1920 chunks
    if (c < 1920) {
      int row = c >> 3, c8 = (c & 7) * 8;
      s16x8 v = *(const s16x8*)(relT + ((long)h * 240 + row) * 64 + c8);
      *(s16x8*)((char*)Bs + row * 128 + ((c8 * 2) ^ ((row & 7) << 4))) = v;
    }
  }
  __syncthreads();

  s16x8 af[2][2];
  #pragma unroll
  for (int mi = 0; mi < 2; mi++) {
    const int row = w * 32 + mi * 16 + l15, sw = (row & 7) << 4;
    af[mi][0] = *(const s16x8*)((char*)As + row * 128 + ((l4 * 16) ^ sw));
    af[mi][1] = *(const s16x8*)((char*)As + row * 128 + ((64 + l4 * 16) ^ sw));
  }
  f32x4 zero = {0.f, 0.f, 0.f, 0.f};
  f32x4 acc[2][15];
  #pragma unroll
  for (int mi = 0; mi < 2; mi++)
    #pragma unroll
    for (int nj = 0; nj < 15; nj++) acc[mi][nj] = zero;
  #pragma unroll
  for (int nj = 0; nj < 15; nj++) {
    const int rb = nj * 16 + l15, sw = (rb & 7) << 4;
    s16x8 b0 = *(const s16x8*)((char*)Bs + rb * 128 + ((l4 * 16) ^ sw));
    s16x8 b1 = *(const s16x8*)((char*)Bs + rb * 128 + ((64 + l4 * 16) ^ sw));
    #pragma unroll
    for (int mi = 0; mi < 2; mi++) {
      acc[mi][nj] = mfma16(af[mi][0], b0, acc[mi][nj]);
      acc[mi][nj] = mfma16(af[mi][1], b1, acc[mi][nj]);
    }
  }
  #pragma unroll
  for (int nj = 0; nj < 15; nj++) {
    const int r = nj * 16 + l15;
    const float dval = Dadd ? Dadd[h * 240 + r] : 0.f;
    #pragma unroll
    for (int mi = 0; mi < 2; mi++) {
      #pragma unroll
      for (int j = 0; j < 4; j++) {
        const int R = bm * 128 + w * 32 + mi * 16 + l4 * 4 + j;
        const int bl = R >> 6, t = R & 63;
        outp[(((long)bl * 16 + h) * 64 + t) * 240 + r] = f2bf(acc[mi][nj][j] + dval);
      }
    }
  }
}

// ---------------- barrier-free fused attention ----------------
// One block per (bl,h); 4 waves; each wave owns 16 t-rows; LDS is wave-private:
// Pb[64][640B]: bytes 0..511 = P (bf16[256], XOR-swizzled), 512..639 = attn bf16[64].
__global__ __launch_bounds__(256, 4) void attn_kernel(
    const short* __restrict__ qkv, const short* __restrict__ qrp,
    const short* __restrict__ krp, const short* __restrict__ relvT,
    const short* __restrict__ vT, const int* __restrict__ rel_index, int b0) {
  __shared__ __attribute__((aligned(16))) char Pb[40960];

  const int tid = threadIdx.x, lane = tid & 63, w = tid >> 6;
  const int l15 = lane & 15, l4 = lane >> 4;
  const int bh = blockIdx.x, bl = bh >> 4, h = bh & 15;
  const int b = b0 + bl;
  const f32x4 zero = {0.f, 0.f, 0.f, 0.f};

  // q fragments from global
  const long qbase = ((long)(b * 64 + w * 16 + l15)) * 3072 + h * 64;
  s16x8 aq0 = *(const s16x8*)(qkv + qbase + l4 * 8);
  s16x8 aq1 = *(const s16x8*)(qkv + qbase + 32 + l4 * 8);

  // S = q @ k^T with k fragments from global
  f32x4 sacc[4];
  sacc[0] = sacc[1] = sacc[2] = sacc[3] = zero;
  #pragma unroll
  for (int n = 0; n < 4; n++) {
    const long kb = ((long)(b * 64 + n * 16 + l15)) * 3072 + 1024 + h * 64;
    s16x8 b0 = *(const s16x8*)(qkv + kb + l4 * 8);
    s16x8 b1 = *(const s16x8*)(qkv + kb + 32 + l4 * 8);
    sacc[n] = mfma16(aq0, b0, sacc[n]);
    sacc[n] = mfma16(aq1, b1, sacc[n]);
  }

  // gather qr' (has Dh absorbed) + kr, scale, softmax (in-place in sacc)
  const short* qrb = qrp + ((long)(bl * 16 + h) * 64) * 240;
  const short* krb = krp + ((long)(bl * 16 + h) * 64) * 240;
  #pragma unroll
  for (int n = 0; n < 4; n++)
    #pragma unroll
    for (int j = 0; j < 4; j++) {
      const int t = w * 16 + l4 * 4 + j, s = n * 16 + l15;
      const int r = rel_index[t * 64 + s];
      sacc[n][j] = (sacc[n][j] + bf2f(qrb[t * 240 + r]) + bf2f(krb[s * 240 + r])) * 0.125f;
    }
  #pragma unroll
  for (int j = 0; j < 4; j++) {
    float m = fmaxf(fmaxf(sacc[0][j], sacc[1][j]), fmaxf(sacc[2][j], sacc[3][j]));
    m = fmaxf(m, __shfl_xor(m, 1));
    m = fmaxf(m, __shfl_xor(m, 2));
    m = fmaxf(m, __shfl_xor(m, 4));
    m = fmaxf(m, __shfl_xor(m, 8));
    float sum = 0.f;
    #pragma unroll
    for (int n = 0; n < 4; n++) { sacc[n][j] = __expf(sacc[n][j] - m); sum += sacc[n][j]; }
    sum += __shfl_xor(sum, 1);
    sum += __shfl_xor(sum, 2);
    sum += __shfl_xor(sum, 4);
    sum += __shfl_xor(sum, 8);
    const float inv = 1.f / sum;
    #pragma unroll
    for (int n = 0; n < 4; n++) sacc[n][j] *= inv;
  }

  // zero wave-own P region (16 rows x 512 B)
  {
    s16x8 z = {0, 0, 0, 0, 0, 0, 0, 0};
    #pragma unroll
    for (int i = 0; i < 8; i++) {
      const int c = lane + 64 * i;             // 512 chunks of 16B
      *(s16x8*)(Pb + (w * 16 + (c >> 5)) * 640 + (c & 31) * 16) = z;
    }
  }
  // scatter P (collision-free) and stage attn, wave-own rows, swizzled
  #pragma unroll
  for (int n = 0; n < 4; n++)
    #pragma unroll
    for (int j = 0; j < 4; j++) {
      const int t = w * 16 + l4 * 4 + j, s = n * 16 + l15;
      const int r = rel_index[t * 64 + s];
      const int sw = (t & 7) << 4;
      const short a = f2bf(sacc[n][j]);
      *(short*)(Pb + t * 640 + ((r * 2) ^ sw)) = a;
      *(short*)(Pb + t * 640 + 512 + ((s * 2) ^ sw)) = a;
    }

  // out = [P | attn] @ [relv^T ; v^T]   (wave-own rows only -> no barrier)
  f32x4 oacc[4];
  oacc[0] = oacc[1] = oacc[2] = oacc[3] = zero;
  const int rowp = w * 16 + l15, px = (rowp & 7) << 4;
  const short* rvh = relvT + (long)h * 16384;
  const short* vTb = vT + ((long)(b * 16 + h)) * 4096;
  #pragma unroll
  for (int kk = 0; kk < 8; kk++) {
    s16x8 pa = *(const s16x8*)(Pb + rowp * 640 + ((kk * 64 + l4 * 16) ^ px));
    #pragma unroll
    for (int n = 0; n < 4; n++) {
      s16x8 bb = *(const s16x8*)(rvh + (n * 16 + l15) * 256 + kk * 32 + l4 * 8);
      oacc[n] = mfma16(pa, bb, oacc[n]);
    }
  }
  #pragma unroll
  for (int ks = 0; ks < 2; ks++) {
    s16x8 pa = *(const s16x8*)(Pb + rowp * 640 + 512 + ((ks * 64 + l4 * 16) ^ px));
    #pragma unroll
    for (int n = 0; n < 4; n++) {
      s16x8 bb = *(const s16x8*)(vTb + (n * 16 + l15) * 64 + ks * 32 + l4 * 8);
      oacc[n] = mfma16(pa, bb, oacc[n]);
    }
  }
  // write into the qkv v-hole (cols 2048..3071) as the O-GEMM's A
  short* outA = (short*)qkv;   // same buffer, disjoint columns
  #pragma unroll
  for (int n = 0; n < 4; n++)
    #pragma unroll
    for (int j = 0; j < 4; j++) {
      const int t = w * 16 + l4 * 4 + j, d = n * 16 + l15;
      outA[((long)(b * 64 + t)) * 3072 + 2048 + h * 64 + d] = f2bf(oacc[n][j]);
    }
}

extern "C" void kernel_launch(void* const* d_in, const int* in_sizes, int n_in,
                              void* d_out, int out_size, void* d_ws, size_t ws_size,
                              hipStream_t stream) {
  const float* x     = (const float*)d_in[0];
  const float* Wq_w  = (const float*)d_in[1];
  const float* Wq_b  = (const float*)d_in[2];
  const float* Wk_w  = (const float*)d_in[3];
  const float* Wk_b  = (const float*)d_in[4];
  const float* Wv_w  = (const float*)d_in[5];
  const float* Wv_b  = (const float*)d_in[6];
  const float* Wo_w  = (const float*)d_in[7];
  const float* Wo_b  = (const float*)d_in[8];
  const float* rel_q = (const float*)d_in[9];
  const float* rel_k = (const float*)d_in[10];
  const float* rel_v = (const float*)d_in[11];
  const int* rel_index = (const int*)d_in[12];
  float* out = (float*)d_out;

  char* ws = (char*)d_ws;
  short* x_bf   = (short*)(ws);                   // 134,217,728
  short* qkv_bf = (short*)(ws + 134217728L);      // 402,653,184 (q|k|attn-out hole)
  short* wq_bf  = (short*)(ws + 536870912L);      // wq|wk|wv contiguous
  short* wo_bf  = (short*)(ws + 543162368L);
  float* biascat= (float*)(ws + 545259520L);
  short* relqb  = (short*)(ws + 545271808L);
  short* relkb  = (short*)(ws + 545763328L);
  short* relvT  = (short*)(ws + 546254848L);
  float* Dh     = (float*)(ws + 546779136L);
  short* qr     = (short*)(ws + 546794496L);      // 125,829,120 (per-chunk)
  short* kr     = (short*)(ws + 672623616L);      // 125,829,120
  short* vT     = (short*)(ws + 798452736L);      // 134,217,728

  cvt_bf16_kernel<<<65536, 256, 0, stream>>>(x, x_bf, 67108864L);
  cvt_bf16_kernel<<<1024, 256, 0, stream>>>(Wq_w, wq_bf, 1048576L);
  cvt_bf16_kernel<<<1024, 256, 0, stream>>>(Wk_w, (short*)(ws + 538968064L), 1048576L);
  cvt_bf16_kernel<<<1024, 256, 0, stream>>>(Wv_w, (short*)(ws + 541065216L), 1048576L);
  cvt_bf16_kernel<<<1024, 256, 0, stream>>>(Wo_w, wo_bf, 1048576L);
  bias_cat_kernel<<<12, 256, 0, stream>>>(Wq_b, Wk_b, Wv_b, biascat);
  prep_rel_kernel<<<3840, 64, 0, stream>>>(rel_q, rel_k, rel_v, relqb, relkb, relvT, Dh);

  // fused QKV projection: q,k row-major into qkv_bf; v transposed into vT
  gemm_bt_kernel<2><<<12288, 256, 0, stream>>>(x_bf, wq_bf, biascat, (void*)qkv_bf, vT,
                                               65536, 3072, 1024, 1024);

  for (int c = 0; c < 4; c++) {
    const int b0 = c * 256;
    qrel_kernel<<<dim3(128, 16), 256, 0, stream>>>(qkv_bf, 0,    relkb, Dh,      qr, b0);
    qrel_kernel<<<dim3(128, 16), 256, 0, stream>>>(qkv_bf, 1024, relqb, nullptr, kr, b0);
    attn_kernel<<<4096, 256, 0, stream>>>(qkv_bf, qr, kr, relvT, vT, rel_index, b0);
  }

  gemm_bt_kernel<0><<<4096, 256, 0, stream>>>(qkv_bf + 2048, wo_bf, Wo_b, (void*)out,
                                              nullptr, 65536, 1024, 1024, 3072);
}

// Round 4
// 1779.337 us; speedup vs baseline: 1.1516x; 1.1516x over previous
//
#include <hip/hip_runtime.h>

typedef __attribute__((ext_vector_type(4))) float f32x4;
typedef __attribute__((ext_vector_type(8))) short s16x8;
typedef __attribute__((ext_vector_type(4))) short s16x4;

__device__ __forceinline__ short f2bf(float f) {
  union { float f; unsigned u; } v; v.f = f;
  unsigned r = (v.u + 0x7fffu + ((v.u >> 16) & 1u)) >> 16;
  return (short)(r & 0xffffu);
}
__device__ __forceinline__ float bf2f(short s) {
  union { unsigned u; float f; } v; v.u = ((unsigned)(unsigned short)s) << 16;
  return v.f;
}
__device__ __forceinline__ f32x4 mfma16(s16x8 a, s16x8 b, f32x4 c) {
  return __builtin_amdgcn_mfma_f32_16x16x32_bf16(a, b, c, 0, 0, 0);
}

#define AS1(p) ((__attribute__((address_space(1))) void*)(p))
#define AS3(p) ((__attribute__((address_space(3))) void*)(p))

// ---------------- fp32 -> bf16 convert ----------------
__global__ __launch_bounds__(256) void cvt_bf16_kernel(const float* __restrict__ in,
                                                       short* __restrict__ out, long n) {
  long i = ((long)blockIdx.x * 256 + threadIdx.x) * 4;
  if (i + 4 <= n) {
    f32x4 v = *(const f32x4*)(in + i);
    s16x4 o;
    o[0] = f2bf(v[0]); o[1] = f2bf(v[1]); o[2] = f2bf(v[2]); o[3] = f2bf(v[3]);
    *(s16x4*)(out + i) = o;
  }
}

// ---------------- concat 3 bias vectors ----------------
__global__ __launch_bounds__(256) void bias_cat_kernel(const float* __restrict__ bq,
                                                       const float* __restrict__ bk,
                                                       const float* __restrict__ bv,
                                                       float* __restrict__ o) {
  int i = blockIdx.x * 256 + threadIdx.x;
  if (i < 3072) o[i] = (i < 1024) ? bq[i] : ((i < 2048) ? bk[i - 1024] : bv[i - 2048]);
}

// ---------------- rel table prep ----------------
__global__ __launch_bounds__(64) void prep_rel_kernel(
    const float* __restrict__ rq, const float* __restrict__ rk, const float* __restrict__ rv,
    short* __restrict__ relqb, short* __restrict__ relkb, short* __restrict__ relvT,
    float* __restrict__ Dh) {
  int h = blockIdx.x / 240;
  int r = blockIdx.x % 240;
  int d = threadIdx.x;
  float vq = 0.f, vk = 0.f, vv = 0.f;
  if (r < 225) {
    long o = ((long)h * 225 + r) * 64 + d;
    vq = rq[o]; vk = rk[o]; vv = rv[o];
  }
  relqb[((long)h * 240 + r) * 64 + d] = f2bf(vq);
  relkb[((long)h * 240 + r) * 64 + d] = f2bf(vk);
  relvT[((long)h * 64 + d) * 256 + r] = f2bf(vv);
  if (r < 16) relvT[((long)h * 64 + d) * 256 + 240 + r] = 0;
  float p = vq * vk;
  #pragma unroll
  for (int m = 32; m >= 1; m >>= 1) p += __shfl_xor(p, m);
  if (d == 0) Dh[h * 240 + r] = p;
}

// ============ 256x256 8-phase GEMM: C = A(M x K, lda) @ Bw(N x K)^T + bias ============
// 512 thr = 8 waves (2M x 4N); BK=64; LDS 128 KiB double-buffered.
// Swizzle: LDS linear, global source pre-swizzled (col16 ^= row&7), reads re-swizzled.
#define BAR  __builtin_amdgcn_s_barrier()
#define LGK0 do { asm volatile("s_waitcnt lgkmcnt(0)" ::: "memory"); \
                  __builtin_amdgcn_sched_barrier(0); } while (0)
#define VM4  asm volatile("s_waitcnt vmcnt(4)" ::: "memory")
#define VM0  asm volatile("s_waitcnt vmcnt(0)" ::: "memory")
#define PRIO1 __builtin_amdgcn_s_setprio(1)
#define PRIO0 __builtin_amdgcn_s_setprio(0)

#define STG_A(D, H, KOFF) do { \
    const short* _s = gA + (long)(H) * 128 * ldaL + (KOFF); \
    char* _d = lds + (D) * 32768 + (H) * 16384 + ldsw; \
    __builtin_amdgcn_global_load_lds(AS1(_s), AS3(_d), 16, 0, 0); \
    __builtin_amdgcn_global_load_lds(AS1(_s + 64 * ldaL), AS3(_d + 8192), 16, 0, 0); \
  } while (0)
#define STG_B(D, H, KOFF) do { \
    const short* _s = gB + (long)(H) * 128 * ldbL + (KOFF); \
    char* _d = lds + 65536 + (D) * 32768 + (H) * 16384 + ldsw; \
    __builtin_amdgcn_global_load_lds(AS1(_s), AS3(_d), 16, 0, 0); \
    __builtin_amdgcn_global_load_lds(AS1(_s + 64 * ldbL), AS3(_d + 8192), 16, 0, 0); \
  } while (0)
#define RD_A(D, MIH) do { \
    const char* _b = lds + (D) * 32768 + baseA + (MIH) * 8192; \
    _Pragma("unroll") for (int i = 0; i < 4; i++) { \
      aa[0][i] = *(const s16x8*)(_b + i * 2048 + cax0); \
      aa[1][i] = *(const s16x8*)(_b + i * 2048 + cax1); \
    } } while (0)
#define RD_B(D, NJH) do { \
    const char* _b = lds + (D) * 32768 + baseB + (NJH) * 4096; \
    _Pragma("unroll") for (int j = 0; j < 2; j++) { \
      bb[0][(NJH) * 2 + j] = *(const s16x8*)(_b + j * 2048 + cax0); \
      bb[1][(NJH) * 2 + j] = *(const s16x8*)(_b + j * 2048 + cax1); \
    } } while (0)
#define MM_Q(MIH, NJH) do { \
    _Pragma("unroll") for (int i = 0; i < 4; i++) { \
      _Pragma("unroll") for (int j = 0; j < 2; j++) { \
        f32x4& c = acc[(MIH) * 4 + i][(NJH) * 2 + j]; \
        c = mfma16(aa[0][i], bb[0][(NJH) * 2 + j], c); \
        c = mfma16(aa[1][i], bb[1][(NJH) * 2 + j], c); \
    } } } while (0)

template<int OUT_BF16>
__global__ __launch_bounds__(512, 2) void gemm256_kernel(
    const short* __restrict__ A, const short* __restrict__ Bw,
    const float* __restrict__ bias, void* __restrict__ Cout,
    int N, int K, int lda) {
  __shared__ __attribute__((aligned(16))) char lds[131072];
  const int tid = threadIdx.x, lane = tid & 63, w = tid >> 6;
  const int wr = w >> 2, wc = w & 3;
  const int l15 = lane & 15, l4 = lane >> 4;
  const int nbn = N >> 8;
  const int nwg = gridDim.x, bid = blockIdx.x;
  const int swz = ((bid & 7) * (nwg >> 3)) + (bid >> 3);   // XCD swizzle (nwg%8==0)
  const int bm = swz / nbn, bn = swz % nbn;

  const int srow = tid >> 3;
  const int scol = ((tid & 7) ^ (srow & 7)) * 8;           // pre-swizzled source chunk
  const long ldaL = lda, ldbL = K;
  const short* gA = A  + ((long)(bm * 256 + srow)) * ldaL + scol;
  const short* gB = Bw + ((long)(bn * 256 + srow)) * ldbL + scol;
  const int ldsw = w * 1024;

  const int baseA = (wr * 128 + l15) * 128;
  const int baseB = 65536 + (wc * 64 + l15) * 128;
  const int cax0 = ((l4) ^ (l15 & 7)) * 16;
  const int cax1 = ((4 + l4) ^ (l15 & 7)) * 16;

  f32x4 acc[8][4];
  #pragma unroll
  for (int i = 0; i < 8; i++)
    #pragma unroll
    for (int j = 0; j < 4; j++) acc[i][j] = (f32x4){0.f, 0.f, 0.f, 0.f};
  s16x8 aa[2][4], bb[2][4];

  // prologue: kt0 fully + B-halves of kt1
  STG_A(0, 0, 0); STG_A(0, 1, 0); STG_B(0, 0, 0); STG_B(0, 1, 0);
  STG_B(1, 0, 64); STG_B(1, 1, 64);
  VM4;                                  // kt0 resident; B(kt1) in flight
  BAR;

  const int NT = K >> 6;
  for (int kt = 0; kt < NT; kt += 2) {
    const int k1 = (kt + 1) << 6, k2 = (kt + 2) << 6, k3 = (kt + 3) << 6;
    const bool full = (kt + 2) < NT;
    // ---- K-tile kt (buf0) ----
    STG_A(1, 0, k1);                              // ph1: A0(kt+1)
    RD_A(0, 0); RD_B(0, 0);
    BAR; LGK0; PRIO1; MM_Q(0, 0); PRIO0; BAR;
    STG_A(1, 1, k1);                              // ph2: A1(kt+1)
    RD_B(0, 1);
    BAR; LGK0; PRIO1; MM_Q(0, 1); PRIO0; BAR;
    if (full) STG_B(0, 0, k2);                    // ph3: B0(kt+2)
    RD_A(0, 1);
    BAR; LGK0; PRIO1; MM_Q(1, 0); PRIO0; BAR;
    if (full) STG_B(0, 1, k2);                    // ph4: B1(kt+2)
    BAR; LGK0; PRIO1; MM_Q(1, 1); PRIO0;
    if (full) { VM4; } else { VM0; }              // kt+1 resident
    BAR;
    // ---- K-tile kt+1 (buf1) ----
    if (full) STG_A(0, 0, k2);                    // ph5: A0(kt+2)
    RD_A(1, 0); RD_B(1, 0);
    BAR; LGK0; PRIO1; MM_Q(0, 0); PRIO0; BAR;
    if (full) STG_A(0, 1, k2);                    // ph6: A1(kt+2)
    RD_B(1, 1);
    BAR; LGK0; PRIO1; MM_Q(0, 1); PRIO0; BAR;
    if (full) STG_B(1, 0, k3);                    // ph7: B0(kt+3)
    RD_A(1, 1);
    BAR; LGK0; PRIO1; MM_Q(1, 0); PRIO0; BAR;
    if (full) STG_B(1, 1, k3);                    // ph8: B1(kt+3)
    BAR; LGK0; PRIO1; MM_Q(1, 1); PRIO0;
    if (full) { VM4; } else { VM0; }              // kt+2 resident
    BAR;
  }

  const long crow = (long)bm * 256 + wr * 128;
  const int ccol = bn * 256 + wc * 64;
  #pragma unroll
  for (int nj = 0; nj < 4; nj++) {
    const int col = ccol + nj * 16 + l15;
    const float bv = bias[col];
    #pragma unroll
    for (int mi = 0; mi < 8; mi++) {
      #pragma unroll
      for (int j = 0; j < 4; j++) {
        const long row = crow + mi * 16 + l4 * 4 + j;
        float val = acc[mi][nj][j] + bv;
        if (OUT_BF16) ((short*)Cout)[row * N + col] = f2bf(val);
        else          ((float*)Cout)[row * N + col] = val;
      }
    }
  }
}

// ---------------- v -> vT[b][h][d][t] transpose ----------------
__global__ __launch_bounds__(256) void vtrans_kernel(const short* __restrict__ qkv,
                                                     short* __restrict__ vT) {
  __shared__ short t[64][80];
  const int tid = threadIdx.x;
  const int bh = blockIdx.x, b = bh >> 4, h = bh & 15;
  const int r = tid >> 2, c = (tid & 3) * 16;
  const long g = ((long)(b * 64 + r)) * 3072 + 2048 + h * 64 + c;
  *(s16x8*)&t[r][c] = *(const s16x8*)(qkv + g);
  *(s16x8*)&t[r][c + 8] = *(const s16x8*)(qkv + g + 8);
  __syncthreads();
  const int d = tid >> 2, t0 = (tid & 3) * 16;
  short* o = vT + ((long)(b * 16 + h)) * 4096 + d * 64 + t0;
  s16x8 v0, v1;
  #pragma unroll
  for (int i = 0; i < 8; i++) { v0[i] = t[t0 + i][d]; v1[i] = t[t0 + 8 + i][d]; }
  *(s16x8*)o = v0;
  *(s16x8*)(o + 8) = v1;
}

// ---------------- qr/kr producer ----------------
__global__ __launch_bounds__(256) void qrel_kernel(
    const short* __restrict__ qkv, int col_off, const short* __restrict__ relT,
    const float* __restrict__ Dadd, short* __restrict__ outp, int b0) {
  __shared__ __attribute__((aligned(16))) short As[8192];   // 128 x 64, swizzled
  __shared__ __attribute__((aligned(16))) short Bs[15360];  // 240 x 64, swizzled
  const int tid = threadIdx.x, lane = tid & 63, w = tid >> 6;
  const int l15 = lane & 15, l4 = lane >> 4;
  const int bm = blockIdx.x, h = blockIdx.y;

  #pragma unroll
  for (int i = 0; i < 4; i++) {
    int c = tid * 4 + i;
    int row = c >> 3, c8 = (c & 7) * 8;
    long g = ((long)(b0 * 64 + bm * 128 + row)) * 3072 + col_off + h * 64 + c8;
    s16x8 v = *(const s16x8*)(qkv + g);
    *(s16x8*)((char*)As + row * 128 + ((c8 * 2) ^ ((row & 7) << 4))) = v;
  }
  #pragma unroll
  for (int i = 0; i < 8; i++) {
    int c = tid + 256 * i;
    if (c < 1920) {
      int row = c >> 3, c8 = (c & 7) * 8;
      s16x8 v = *(const s16x8*)(relT + ((long)h * 240 + row) * 64 + c8);
      *(s16x8*)((char*)Bs + row * 128 + ((c8 * 2) ^ ((row & 7) << 4))) = v;
    }
  }
  __syncthreads();

  s16x8 af[2][2];
  #pragma unroll
  for (int mi = 0; mi < 2; mi++) {
    const int row = w * 32 + mi * 16 + l15, sw = (row & 7) << 4;
    af[mi][0] = *(const s16x8*)((char*)As + row * 128 + ((l4 * 16) ^ sw));
    af[mi][1] = *(const s16x8*)((char*)As + row * 128 + ((64 + l4 * 16) ^ sw));
  }
  f32x4 zero = {0.f, 0.f, 0.f, 0.f};
  f32x4 acc[2][15];
  #pragma unroll
  for (int mi = 0; mi < 2; mi++)
    #pragma unroll
    for (int nj = 0; nj < 15; nj++) acc[mi][nj] = zero;
  #pragma unroll
  for (int nj = 0; nj < 15; nj++) {
    const int rb = nj * 16 + l15, sw = (rb & 7) << 4;
    s16x8 b0 = *(const s16x8*)((char*)Bs + rb * 128 + ((l4 * 16) ^ sw));
    s16x8 b1 = *(const s16x8*)((char*)Bs + rb * 128 + ((64 + l4 * 16) ^ sw));
    #pragma unroll
    for (int mi = 0; mi < 2; mi++) {
      acc[mi][nj] = mfma16(af[mi][0], b0, acc[mi][nj]);
      acc[mi][nj] = mfma16(af[mi][1], b1, acc[mi][nj]);
    }
  }
  #pragma unroll
  for (int nj = 0; nj < 15; nj++) {
    const int r = nj * 16 + l15;
    const float dval = Dadd ? Dadd[h * 240 + r] : 0.f;
    #pragma unroll
    for (int mi = 0; mi < 2; mi++) {
      #pragma unroll
      for (int j = 0; j < 4; j++) {
        const int R = bm * 128 + w * 32 + mi * 16 + l4 * 4 + j;
        const int bl = R >> 6, t = R & 63;
        outp[(((long)bl * 16 + h) * 64 + t) * 240 + r] = f2bf(acc[mi][nj][j] + dval);
      }
    }
  }
}

// ---------------- barrier-free fused attention ----------------
__global__ __launch_bounds__(256, 4) void attn_kernel(
    const short* __restrict__ qkv, const short* __restrict__ qrp,
    const short* __restrict__ krp, const short* __restrict__ relvT,
    const short* __restrict__ vT, const int* __restrict__ rel_index,
    short* __restrict__ aout, int b0) {
  __shared__ __attribute__((aligned(16))) char Pb[40960];

  const int tid = threadIdx.x, lane = tid & 63, w = tid >> 6;
  const int l15 = lane & 15, l4 = lane >> 4;
  const int bh = blockIdx.x, bl = bh >> 4, h = bh & 15;
  const int b = b0 + bl;
  const f32x4 zero = {0.f, 0.f, 0.f, 0.f};

  const long qbase = ((long)(b * 64 + w * 16 + l15)) * 3072 + h * 64;
  s16x8 aq0 = *(const s16x8*)(qkv + qbase + l4 * 8);
  s16x8 aq1 = *(const s16x8*)(qkv + qbase + 32 + l4 * 8);

  f32x4 sacc[4];
  sacc[0] = sacc[1] = sacc[2] = sacc[3] = zero;
  #pragma unroll
  for (int n = 0; n < 4; n++) {
    const long kb = ((long)(b * 64 + n * 16 + l15)) * 3072 + 1024 + h * 64;
    s16x8 b0 = *(const s16x8*)(qkv + kb + l4 * 8);
    s16x8 b1 = *(const s16x8*)(qkv + kb + 32 + l4 * 8);
    sacc[n] = mfma16(aq0, b0, sacc[n]);
    sacc[n] = mfma16(aq1, b1, sacc[n]);
  }

  const short* qrb = qrp + ((long)(bl * 16 + h) * 64) * 240;
  const short* krb = krp + ((long)(bl * 16 + h) * 64) * 240;
  #pragma unroll
  for (int n = 0; n < 4; n++)
    #pragma unroll
    for (int j = 0; j < 4; j++) {
      const int t = w * 16 + l4 * 4 + j, s = n * 16 + l15;
      const int r = rel_index[t * 64 + s];
      sacc[n][j] = (sacc[n][j] + bf2f(qrb[t * 240 + r]) + bf2f(krb[s * 240 + r])) * 0.125f;
    }
  #pragma unroll
  for (int j = 0; j < 4; j++) {
    float m = fmaxf(fmaxf(sacc[0][j], sacc[1][j]), fmaxf(sacc[2][j], sacc[3][j]));
    m = fmaxf(m, __shfl_xor(m, 1));
    m = fmaxf(m, __shfl_xor(m, 2));
    m = fmaxf(m, __shfl_xor(m, 4));
    m = fmaxf(m, __shfl_xor(m, 8));
    float sum = 0.f;
    #pragma unroll
    for (int n = 0; n < 4; n++) { sacc[n][j] = __expf(sacc[n][j] - m); sum += sacc[n][j]; }
    sum += __shfl_xor(sum, 1);
    sum += __shfl_xor(sum, 2);
    sum += __shfl_xor(sum, 4);
    sum += __shfl_xor(sum, 8);
    const float inv = 1.f / sum;
    #pragma unroll
    for (int n = 0; n < 4; n++) sacc[n][j] *= inv;
  }

  {
    s16x8 z = {0, 0, 0, 0, 0, 0, 0, 0};
    #pragma unroll
    for (int i = 0; i < 8; i++) {
      const int c = lane + 64 * i;
      *(s16x8*)(Pb + (w * 16 + (c >> 5)) * 640 + (c & 31) * 16) = z;
    }
  }
  #pragma unroll
  for (int n = 0; n < 4; n++)
    #pragma unroll
    for (int j = 0; j < 4; j++) {
      const int t = w * 16 + l4 * 4 + j, s = n * 16 + l15;
      const int r = rel_index[t * 64 + s];
      const int sw = (t & 7) << 4;
      const short a = f2bf(sacc[n][j]);
      *(short*)(Pb + t * 640 + ((r * 2) ^ sw)) = a;
      *(short*)(Pb + t * 640 + 512 + ((s * 2) ^ sw)) = a;
    }

  f32x4 oacc[4];
  oacc[0] = oacc[1] = oacc[2] = oacc[3] = zero;
  const int rowp = w * 16 + l15, px = (rowp & 7) << 4;
  const short* rvh = relvT + (long)h * 16384;
  const short* vTb = vT + ((long)(b * 16 + h)) * 4096;
  #pragma unroll
  for (int kk = 0; kk < 8; kk++) {
    s16x8 pa = *(const s16x8*)(Pb + rowp * 640 + ((kk * 64 + l4 * 16) ^ px));
    #pragma unroll
    for (int n = 0; n < 4; n++) {
      s16x8 bbv = *(const s16x8*)(rvh + (n * 16 + l15) * 256 + kk * 32 + l4 * 8);
      oacc[n] = mfma16(pa, bbv, oacc[n]);
    }
  }
  #pragma unroll
  for (int ks = 0; ks < 2; ks++) {
    s16x8 pa = *(const s16x8*)(Pb + rowp * 640 + 512 + ((ks * 64 + l4 * 16) ^ px));
    #pragma unroll
    for (int n = 0; n < 4; n++) {
      s16x8 bbv = *(const s16x8*)(vTb + (n * 16 + l15) * 64 + ks * 32 + l4 * 8);
      oacc[n] = mfma16(pa, bbv, oacc[n]);
    }
  }
  #pragma unroll
  for (int n = 0; n < 4; n++)
    #pragma unroll
    for (int j = 0; j < 4; j++) {
      const int t = w * 16 + l4 * 4 + j, d = n * 16 + l15;
      aout[((long)(b * 64 + t)) * 1024 + h * 64 + d] = f2bf(oacc[n][j]);
    }
}

extern "C" void kernel_launch(void* const* d_in, const int* in_sizes, int n_in,
                              void* d_out, int out_size, void* d_ws, size_t ws_size,
                              hipStream_t stream) {
  const float* x     = (const float*)d_in[0];
  const float* Wq_w  = (const float*)d_in[1];
  const float* Wq_b  = (const float*)d_in[2];
  const float* Wk_w  = (const float*)d_in[3];
  const float* Wk_b  = (const float*)d_in[4];
  const float* Wv_w  = (const float*)d_in[5];
  const float* Wv_b  = (const float*)d_in[6];
  const float* Wo_w  = (const float*)d_in[7];
  const float* Wo_b  = (const float*)d_in[8];
  const float* rel_q = (const float*)d_in[9];
  const float* rel_k = (const float*)d_in[10];
  const float* rel_v = (const float*)d_in[11];
  const int* rel_index = (const int*)d_in[12];
  float* out = (float*)d_out;

  char* ws = (char*)d_ws;
  short* x_bf   = (short*)(ws);                   // 134,217,728 (reused as aout)
  short* qkv_bf = (short*)(ws + 134217728L);      // 402,653,184
  short* wq_bf  = (short*)(ws + 536870912L);      // wq|wk|wv contiguous
  short* wo_bf  = (short*)(ws + 543162368L);
  float* biascat= (float*)(ws + 545259520L);
  short* relqb  = (short*)(ws + 545271808L);
  short* relkb  = (short*)(ws + 545763328L);
  short* relvT  = (short*)(ws + 546254848L);
  float* Dh     = (float*)(ws + 546779136L);
  short* qr     = (short*)(ws + 546794496L);      // 125,829,120 (per-chunk)
  short* kr     = (short*)(ws + 672623616L);      // 125,829,120
  short* vT     = (short*)(ws + 798452736L);      // 134,217,728
  short* aout   = x_bf;

  cvt_bf16_kernel<<<65536, 256, 0, stream>>>(x, x_bf, 67108864L);
  cvt_bf16_kernel<<<1024, 256, 0, stream>>>(Wq_w, wq_bf, 1048576L);
  cvt_bf16_kernel<<<1024, 256, 0, stream>>>(Wk_w, (short*)(ws + 538968064L), 1048576L);
  cvt_bf16_kernel<<<1024, 256, 0, stream>>>(Wv_w, (short*)(ws + 541065216L), 1048576L);
  cvt_bf16_kernel<<<1024, 256, 0, stream>>>(Wo_w, wo_bf, 1048576L);
  bias_cat_kernel<<<12, 256, 0, stream>>>(Wq_b, Wk_b, Wv_b, biascat);
  prep_rel_kernel<<<3840, 64, 0, stream>>>(rel_q, rel_k, rel_v, relqb, relkb, relvT, Dh);

  // fused QKV projection (plain bf16 epilogue)
  gemm256_kernel<1><<<3072, 512, 0, stream>>>(x_bf, wq_bf, biascat, (void*)qkv_bf,
                                              3072, 1024, 1024);
  vtrans_kernel<<<16384, 256, 0, stream>>>(qkv_bf, vT);

  for (int c = 0; c < 4; c++) {
    const int b0 = c * 256;
    qrel_kernel<<<dim3(128, 16), 256, 0, stream>>>(qkv_bf, 0,    relkb, Dh,      qr, b0);
    qrel_kernel<<<dim3(128, 16), 256, 0, stream>>>(qkv_bf, 1024, relqb, nullptr, kr, b0);
    attn_kernel<<<4096, 256, 0, stream>>>(qkv_bf, qr, kr, relvT, vT, rel_index, aout, b0);
  }

  gemm256_kernel<0><<<1024, 512, 0, stream>>>(aout, wo_bf, Wo_b, (void*)out,
                                              1024, 1024, 1024);
}